// Round 1
// 936.939 us; speedup vs baseline: 1.2985x; 1.2985x over previous
//
#include <hip/hip_runtime.h>
#include <stdint.h>

// Round 4:
//  - SpMM rewritten: CSR-permuted (dstp, valp) arrays kill the eidx
//    indirection; one wave per node with float4 row gathers (64 lanes x 4
//    = 256 features, fully coalesced); edge metadata batch-loaded by lanes
//    0..31 and broadcast via __shfl -> dependent-load chain collapsed.
//  - Decoder: when ws_size allows (3.2 MB), z is pre-converted to bf16 in
//    d_ws and the decoder reads bf16 (half the read traffic, half the
//    cacheline requests per strided load, no in-loop f2b). fp32 fallback
//    (identical to R3 decoder) when ws is too small.
//  - Scratch still lives inside d_out[0 : N*N]; all scratch dead before
//    k_decoder overwrites the region.

#define NN 12288   // nodes
#define FF 512     // input feature dim
#define HD1 256    // hidden 1
#define HD2 128    // latent
#define EE 393216  // edges  (EE % 256 == 0)

typedef short bf16x8 __attribute__((ext_vector_type(8)));   // 8 bf16 in 4 VGPRs
typedef float f32x16 __attribute__((ext_vector_type(16)));

__device__ inline unsigned short f2b(float f) {
  // fp32 -> bf16 round-to-nearest-even (inputs finite)
  unsigned int u = __float_as_uint(f);
  unsigned int r = u + 0x7fffu + ((u >> 16) & 1u);
  return (unsigned short)(r >> 16);
}

__device__ inline bf16x8 ldb8(const unsigned short* p) {
  return *(const bf16x8*)p;
}

// load 8 fp32, convert to bf16 fragment
__device__ inline bf16x8 ldf8(const float* p) {
  float4 v0 = ((const float4*)p)[0];
  float4 v1 = ((const float4*)p)[1];
  bf16x8 r;
  r[0] = (short)f2b(v0.x); r[1] = (short)f2b(v0.y);
  r[2] = (short)f2b(v0.z); r[3] = (short)f2b(v0.w);
  r[4] = (short)f2b(v1.x); r[5] = (short)f2b(v1.y);
  r[6] = (short)f2b(v1.z); r[7] = (short)f2b(v1.w);
  return r;
}

__device__ inline f32x16 mfma32(bf16x8 a, bf16x8 b, f32x16 c) {
  return __builtin_amdgcn_mfma_f32_32x32x16_bf16(a, b, c, 0, 0, 0);
}

// ---------------- CSR build ----------------

__global__ void k_hist(const int* __restrict__ src, int* __restrict__ deg) {
  int e = blockIdx.x * 256 + threadIdx.x;   // EE multiple of 256
  atomicAdd(&deg[src[e]], 1);
}

__global__ void k_scan(const int* __restrict__ deg, int* __restrict__ off,
                       int* __restrict__ cur) {
  __shared__ int sdata[256];
  __shared__ int sbase;
  if (threadIdx.x == 0) sbase = 0;
  __syncthreads();
  for (int c = 0; c < NN; c += 256) {   // NN multiple of 256
    int v = deg[c + threadIdx.x];
    sdata[threadIdx.x] = v;
    __syncthreads();
    for (int s = 1; s < 256; s <<= 1) {
      int t = (threadIdx.x >= s) ? sdata[threadIdx.x - s] : 0;
      __syncthreads();
      sdata[threadIdx.x] += t;
      __syncthreads();
    }
    int o = sbase + sdata[threadIdx.x] - v;
    off[c + threadIdx.x] = o;
    cur[c + threadIdx.x] = o;
    __syncthreads();
    if (threadIdx.x == 255) sbase += sdata[255];
    __syncthreads();
  }
}

// permute (dst, val) into CSR order -> contiguous metadata for the SpMMs
__global__ void k_fill(const int* __restrict__ src, const int* __restrict__ dst,
                       const float* __restrict__ ev, int* __restrict__ cur,
                       int* __restrict__ dstp, float* __restrict__ valp) {
  int e = blockIdx.x * 256 + threadIdx.x;
  int p = atomicAdd(&cur[src[e]], 1);
  dstp[p] = dst[e];
  valp[p] = ev[e];
}

// ---------------- dtype prep ----------------

__global__ void k_f2b4(const float* __restrict__ in, unsigned short* __restrict__ outb) {
  int i = blockIdx.x * 256 + threadIdx.x;   // each thread converts 4
  float4 v = ((const float4*)in)[i];
  ushort4 o;
  o.x = f2b(v.x); o.y = f2b(v.y); o.z = f2b(v.z); o.w = f2b(v.w);
  ((ushort4*)outb)[i] = o;
}

// W [K, Ncols] fp32 row-major -> Wt [Ncols, K] bf16 row-major
__global__ void k_transw(const float* __restrict__ W, unsigned short* __restrict__ Wt,
                         int K, int Ncols) {
  int idx = blockIdx.x * 256 + threadIdx.x;
  if (idx < K * Ncols) {
    int k = idx / Ncols;
    int n = idx - k * Ncols;
    Wt[(size_t)n * K + k] = f2b(W[idx]);
  }
}

// ---------------- GEMM: C[M,Nn] = A[M,K] * Bt[Nn,K]^T  (bf16 in, fp32 out) ----------------

__global__ __launch_bounds__(256) void gemm_bt(
    const unsigned short* __restrict__ A, const unsigned short* __restrict__ Bt,
    float* __restrict__ C, int Nn, int K) {
  int wave = threadIdx.x >> 6, lane = threadIdx.x & 63;
  int wr = wave >> 1, wc = wave & 1;
  int row0 = blockIdx.x * 128 + wr * 64;
  int col0 = blockIdx.y * 128 + wc * 64;
  int lm = lane & 31, lk = (lane >> 5) * 8;

  f32x16 acc[2][2] = {};
  const unsigned short* a0p = A + (size_t)(row0 + lm) * K + lk;
  const unsigned short* a1p = a0p + (size_t)32 * K;
  const unsigned short* b0p = Bt + (size_t)(col0 + lm) * K + lk;
  const unsigned short* b1p = b0p + (size_t)32 * K;

  for (int k0 = 0; k0 < K; k0 += 16) {
    bf16x8 a0 = ldb8(a0p + k0), a1 = ldb8(a1p + k0);
    bf16x8 b0 = ldb8(b0p + k0), b1 = ldb8(b1p + k0);
    acc[0][0] = mfma32(a0, b0, acc[0][0]);
    acc[0][1] = mfma32(a0, b1, acc[0][1]);
    acc[1][0] = mfma32(a1, b0, acc[1][0]);
    acc[1][1] = mfma32(a1, b1, acc[1][1]);
  }

#pragma unroll
  for (int ti = 0; ti < 2; ++ti)
#pragma unroll
    for (int tj = 0; tj < 2; ++tj)
#pragma unroll
      for (int r = 0; r < 16; ++r) {
        int row = row0 + ti * 32 + (r & 3) + 8 * (r >> 2) + 4 * (lane >> 5);
        int col = col0 + tj * 32 + lm;
        C[(size_t)row * Nn + col] = acc[ti][tj][r];
      }
}

// ---------------- SpMM (CSR gather, wave-per-node, float4) ----------------

// h1b[i,:] = bf16(relu( sum_e val[e]*sup1[dst[e],:] )), D = 256
__global__ __launch_bounds__(256) void k_spmm_relu(
    const int* __restrict__ off, const int* __restrict__ dstp,
    const float* __restrict__ valp, const float* __restrict__ dense,
    unsigned short* __restrict__ outb) {
  int node = blockIdx.x * 4 + (threadIdx.x >> 6);
  int lane = threadIdx.x & 63;
  int e0 = off[node];
  int e1 = (node == NN - 1) ? EE : off[node + 1];
  const float4* dp = (const float4*)dense;   // row = 64 float4
  float4 acc = make_float4(0.f, 0.f, 0.f, 0.f);
  for (int eb = e0; eb < e1; eb += 32) {
    int rem = e1 - eb; if (rem > 32) rem = 32;
    int dd = 0; float vv = 0.f;
    if (lane < rem) { dd = dstp[eb + lane]; vv = valp[eb + lane]; }
    for (int j = 0; j < rem; ++j) {
      int dj = __shfl(dd, j);
      float vj = __shfl(vv, j);
      float4 r = dp[(size_t)dj * 64 + lane];
      acc.x = fmaf(vj, r.x, acc.x);
      acc.y = fmaf(vj, r.y, acc.y);
      acc.z = fmaf(vj, r.z, acc.z);
      acc.w = fmaf(vj, r.w, acc.w);
    }
  }
  ushort4 ob;
  ob.x = f2b(fmaxf(acc.x, 0.f));
  ob.y = f2b(fmaxf(acc.y, 0.f));
  ob.z = f2b(fmaxf(acc.z, 0.f));
  ob.w = f2b(fmaxf(acc.w, 0.f));
  ((ushort4*)outb)[(size_t)node * 64 + lane] = ob;
}

// mu/logvar from sup23 [N, 256]; write fp32 to d_out tail
__global__ __launch_bounds__(256) void k_spmm_mlv(
    const int* __restrict__ off, const int* __restrict__ dstp,
    const float* __restrict__ valp, const float* __restrict__ dense,
    float* __restrict__ mu, float* __restrict__ logvar) {
  int node = blockIdx.x * 4 + (threadIdx.x >> 6);
  int lane = threadIdx.x & 63;
  int e0 = off[node];
  int e1 = (node == NN - 1) ? EE : off[node + 1];
  const float4* dp = (const float4*)dense;   // row = 64 float4
  float4 acc = make_float4(0.f, 0.f, 0.f, 0.f);
  for (int eb = e0; eb < e1; eb += 32) {
    int rem = e1 - eb; if (rem > 32) rem = 32;
    int dd = 0; float vv = 0.f;
    if (lane < rem) { dd = dstp[eb + lane]; vv = valp[eb + lane]; }
    for (int j = 0; j < rem; ++j) {
      int dj = __shfl(dd, j);
      float vj = __shfl(vv, j);
      float4 r = dp[(size_t)dj * 64 + lane];
      acc.x = fmaf(vj, r.x, acc.x);
      acc.y = fmaf(vj, r.y, acc.y);
      acc.z = fmaf(vj, r.z, acc.z);
      acc.w = fmaf(vj, r.w, acc.w);
    }
  }
  // lanes 0..31 -> features 0..127 = mu; lanes 32..63 -> logvar
  if (lane < 32) ((float4*)mu)[(size_t)node * 32 + lane] = acc;
  else           ((float4*)logvar)[(size_t)node * 32 + (lane - 32)] = acc;
}

// ---------------- Decoder: out = sigmoid(Z * Z^T), Z = mu [NN, 128] ----------------

// bf16-Z variant (Z pre-converted into d_ws)
__global__ __launch_bounds__(256) void k_decoder_b(const unsigned short* __restrict__ Zb,
                                                   float* __restrict__ out) {
  int wave = threadIdx.x >> 6, lane = threadIdx.x & 63;
  int wr = wave >> 1, wc = wave & 1;
  int row0 = blockIdx.x * 128 + wr * 64;
  int col0 = blockIdx.y * 128 + wc * 64;
  int lm = lane & 31, lk = (lane >> 5) * 8;

  f32x16 acc[2][2] = {};
  const unsigned short* a0p = Zb + (size_t)(row0 + lm) * HD2 + lk;
  const unsigned short* a1p = a0p + (size_t)32 * HD2;
  const unsigned short* b0p = Zb + (size_t)(col0 + lm) * HD2 + lk;
  const unsigned short* b1p = b0p + (size_t)32 * HD2;

#pragma unroll
  for (int k0 = 0; k0 < HD2; k0 += 16) {
    bf16x8 a0 = ldb8(a0p + k0), a1 = ldb8(a1p + k0);
    bf16x8 b0 = ldb8(b0p + k0), b1 = ldb8(b1p + k0);
    acc[0][0] = mfma32(a0, b0, acc[0][0]);
    acc[0][1] = mfma32(a0, b1, acc[0][1]);
    acc[1][0] = mfma32(a1, b0, acc[1][0]);
    acc[1][1] = mfma32(a1, b1, acc[1][1]);
  }

#pragma unroll
  for (int ti = 0; ti < 2; ++ti)
#pragma unroll
    for (int tj = 0; tj < 2; ++tj)
#pragma unroll
      for (int r = 0; r < 16; ++r) {
        int row = row0 + ti * 32 + (r & 3) + 8 * (r >> 2) + 4 * (lane >> 5);
        int col = col0 + tj * 32 + lm;
        float v = acc[ti][tj][r];
        out[(size_t)row * NN + col] = 1.0f / (1.0f + __expf(-v));
      }
}

// fp32-Z fallback (identical to R3) when ws is too small for bf16 Z
__global__ __launch_bounds__(256) void k_decoder(const float* __restrict__ Zf,
                                                 float* __restrict__ out) {
  int wave = threadIdx.x >> 6, lane = threadIdx.x & 63;
  int wr = wave >> 1, wc = wave & 1;
  int row0 = blockIdx.x * 128 + wr * 64;
  int col0 = blockIdx.y * 128 + wc * 64;
  int lm = lane & 31, lk = (lane >> 5) * 8;

  f32x16 acc[2][2] = {};
  const float* a0p = Zf + (size_t)(row0 + lm) * HD2 + lk;
  const float* a1p = a0p + (size_t)32 * HD2;
  const float* b0p = Zf + (size_t)(col0 + lm) * HD2 + lk;
  const float* b1p = b0p + (size_t)32 * HD2;

#pragma unroll
  for (int k0 = 0; k0 < HD2; k0 += 16) {
    bf16x8 a0 = ldf8(a0p + k0), a1 = ldf8(a1p + k0);
    bf16x8 b0 = ldf8(b0p + k0), b1 = ldf8(b1p + k0);
    acc[0][0] = mfma32(a0, b0, acc[0][0]);
    acc[0][1] = mfma32(a0, b1, acc[0][1]);
    acc[1][0] = mfma32(a1, b0, acc[1][0]);
    acc[1][1] = mfma32(a1, b1, acc[1][1]);
  }

#pragma unroll
  for (int ti = 0; ti < 2; ++ti)
#pragma unroll
    for (int tj = 0; tj < 2; ++tj)
#pragma unroll
      for (int r = 0; r < 16; ++r) {
        int row = row0 + ti * 32 + (r & 3) + 8 * (r >> 2) + 4 * (lane >> 5);
        int col = col0 + tj * 32 + lm;
        float v = acc[ti][tj][r];
        out[(size_t)row * NN + col] = 1.0f / (1.0f + __expf(-v));
      }
}

// ---------------- launch ----------------

extern "C" void kernel_launch(void* const* d_in, const int* in_sizes, int n_in,
                              void* d_out, int out_size, void* d_ws, size_t ws_size,
                              hipStream_t stream) {
  const float* x  = (const float*)d_in[0];
  const int*   src = (const int*)d_in[1];
  const int*   dst = (const int*)d_in[2];
  const float* ev  = (const float*)d_in[3];
  const float* W1  = (const float*)d_in[4];
  const float* W2  = (const float*)d_in[5];
  const float* W3  = (const float*)d_in[6];
  float* out = (float*)d_out;
  float* mu     = out + (size_t)NN * NN;
  float* logvar = mu + (size_t)NN * HD2;

  // Scratch lives inside out[0 : NN*NN] (604 MB; we need ~48 MB). Every
  // scratch byte is dead before the decoder overwrites the region.
  char* p = (char*)d_out;
  auto alloc = [&](size_t bytes) {
    char* r = p;
    p += (bytes + 255) & ~(size_t)255;
    return r;
  };
  unsigned short* xb   = (unsigned short*)alloc((size_t)NN * FF * 2);
  unsigned short* W1t  = (unsigned short*)alloc((size_t)HD1 * FF * 2);
  unsigned short* W23t = (unsigned short*)alloc((size_t)2 * HD2 * HD1 * 2);
  float*          sup1 = (float*)alloc((size_t)NN * HD1 * 4);
  unsigned short* h1b  = (unsigned short*)alloc((size_t)NN * HD1 * 2);
  float*         sup23 = (float*)alloc((size_t)NN * 2 * HD2 * 4);
  int* deg  = (int*)alloc(NN * 4);
  int* off  = (int*)alloc(NN * 4);
  int* cur  = (int*)alloc(NN * 4);
  int*   dstp = (int*)alloc((size_t)EE * 4);
  float* valp = (float*)alloc((size_t)EE * 4);

  // bf16 Z for the decoder goes into d_ws iff it fits (3.15 MB); it must
  // NOT live in out[0:NN*NN] (the decoder overwrites that region while
  // other blocks still read Z).
  const size_t zb_bytes = (size_t)NN * HD2 * 2;
  bool use_zb = (d_ws != nullptr) && (ws_size >= zb_bytes + 256);
  unsigned short* zb = (unsigned short*)d_ws;

  // CSR build on src (permuting dst/val into CSR order)
  hipMemsetAsync(deg, 0, NN * 4, stream);
  k_hist<<<EE / 256, 256, 0, stream>>>(src, deg);
  k_scan<<<1, 256, 0, stream>>>(deg, off, cur);
  k_fill<<<EE / 256, 256, 0, stream>>>(src, dst, ev, cur, dstp, valp);

  // dtype prep
  k_f2b4<<<(NN * FF / 4) / 256, 256, 0, stream>>>(x, xb);
  k_transw<<<(FF * HD1 + 255) / 256, 256, 0, stream>>>(W1, W1t, FF, HD1);
  k_transw<<<(HD1 * HD2 + 255) / 256, 256, 0, stream>>>(W2, W23t, HD1, HD2);
  k_transw<<<(HD1 * HD2 + 255) / 256, 256, 0, stream>>>(W3, W23t + (size_t)HD2 * HD1, HD1, HD2);

  // encoder layer 1: sup1 = x @ W1 ; h1 = relu(spmm(sup1))
  gemm_bt<<<dim3(NN / 128, HD1 / 128), 256, 0, stream>>>(xb, W1t, sup1, HD1, FF);
  k_spmm_relu<<<NN / 4, 256, 0, stream>>>(off, dstp, valp, sup1, h1b);

  // encoder layer 2 (mu|logvar fused): sup23 = h1 @ [W2|W3] ; spmm -> mu,logvar
  gemm_bt<<<dim3(NN / 128, (2 * HD2) / 128), 256, 0, stream>>>(h1b, W23t, sup23, 2 * HD2, HD1);
  k_spmm_mlv<<<NN / 4, 256, 0, stream>>>(off, dstp, valp, sup23, mu, logvar);

  // decoder: out[0 : NN*NN] = sigmoid(mu @ mu^T)  (z = mu in eval mode)
  if (use_zb) {
    k_f2b4<<<(NN * HD2 / 4) / 256, 256, 0, stream>>>(mu, zb);
    k_decoder_b<<<dim3(NN / 128, NN / 128), 256, 0, stream>>>(zb, out);
  } else {
    k_decoder<<<dim3(NN / 128, NN / 128), 256, 0, stream>>>(mu, out);
  }
}

// Round 2
// 845.025 us; speedup vs baseline: 1.4398x; 1.1088x over previous
//
#include <hip/hip_runtime.h>
#include <stdint.h>

// Round 5:
//  - SpMM inner loop: full 32-edge batches unrolled (#pragma unroll 32) so
//    the compiler lowers __shfl(x, const_j) to v_readlane + issues the 32
//    independent float4 gathers deeply pipelined; dynamic loop only for the
//    <32 tail.
//  - k_scan (1 workgroup, serial over 48 chunks) replaced by a 3-stage
//    parallel scan (48-block local scan -> 1-wave scan of 48 block sums ->
//    offset add). No more single-CU serialization.
//  - Prep kernels fused into one (x->bf16 + 3 weight transposes).
//  - mu->bf16 (decoder input) fused into k_spmm_mlv's write phase.
//  - Decoder epilogue: v_rcp_f32 instead of exact fp32 divide (1-ulp),
//    nontemporal stores for the 604 MB output stream.

#define NN 12288   // nodes
#define FF 512     // input feature dim
#define HD1 256    // hidden 1
#define HD2 128    // latent
#define EE 393216  // edges  (EE % 256 == 0)

typedef short bf16x8 __attribute__((ext_vector_type(8)));   // 8 bf16 in 4 VGPRs
typedef float f32x16 __attribute__((ext_vector_type(16)));

__device__ inline unsigned short f2b(float f) {
  // fp32 -> bf16 round-to-nearest-even (inputs finite)
  unsigned int u = __float_as_uint(f);
  unsigned int r = u + 0x7fffu + ((u >> 16) & 1u);
  return (unsigned short)(r >> 16);
}

__device__ inline bf16x8 ldb8(const unsigned short* p) {
  return *(const bf16x8*)p;
}

// load 8 fp32, convert to bf16 fragment
__device__ inline bf16x8 ldf8(const float* p) {
  float4 v0 = ((const float4*)p)[0];
  float4 v1 = ((const float4*)p)[1];
  bf16x8 r;
  r[0] = (short)f2b(v0.x); r[1] = (short)f2b(v0.y);
  r[2] = (short)f2b(v0.z); r[3] = (short)f2b(v0.w);
  r[4] = (short)f2b(v1.x); r[5] = (short)f2b(v1.y);
  r[6] = (short)f2b(v1.z); r[7] = (short)f2b(v1.w);
  return r;
}

__device__ inline f32x16 mfma32(bf16x8 a, bf16x8 b, f32x16 c) {
  return __builtin_amdgcn_mfma_f32_32x32x16_bf16(a, b, c, 0, 0, 0);
}

__device__ inline float sigmoid_fast(float v) {
  return __builtin_amdgcn_rcpf(1.0f + __expf(-v));   // v_rcp_f32: 1 ulp
}

// ---------------- CSR build ----------------

__global__ void k_hist(const int* __restrict__ src, int* __restrict__ deg) {
  int e = blockIdx.x * 256 + threadIdx.x;   // EE multiple of 256
  atomicAdd(&deg[src[e]], 1);
}

// stage 1: per-256-chunk exclusive scan + chunk total
__global__ void k_scan1(const int* __restrict__ deg, int* __restrict__ off,
                        int* __restrict__ bsum) {
  __shared__ int sdata[256];
  int t = threadIdx.x;
  int i = blockIdx.x * 256 + t;
  int v = deg[i];
  sdata[t] = v;
  __syncthreads();
  for (int s = 1; s < 256; s <<= 1) {
    int u = (t >= s) ? sdata[t - s] : 0;
    __syncthreads();
    sdata[t] += u;
    __syncthreads();
  }
  off[i] = sdata[t] - v;                 // exclusive within chunk
  if (t == 255) bsum[blockIdx.x] = sdata[255];
}

// stage 2: one wave scans the 48 chunk totals -> exclusive chunk offsets
__global__ void k_scan2(int* __restrict__ bsum) {
  int t = threadIdx.x;                   // 64 threads
  int orig = (t < NN / 256) ? bsum[t] : 0;
  int v = orig;
  for (int s = 1; s < 64; s <<= 1) {
    int u = __shfl_up(v, s);
    if (t >= s) v += u;
  }
  if (t < NN / 256) bsum[t] = v - orig;  // exclusive
}

// stage 3: add chunk offsets, init cur
__global__ void k_scan3(const int* __restrict__ bsum, int* __restrict__ off,
                        int* __restrict__ cur) {
  int i = blockIdx.x * 256 + threadIdx.x;
  int o = off[i] + bsum[blockIdx.x];
  off[i] = o;
  cur[i] = o;
}

// permute (dst, val) into CSR order -> contiguous metadata for the SpMMs
__global__ void k_fill(const int* __restrict__ src, const int* __restrict__ dst,
                       const float* __restrict__ ev, int* __restrict__ cur,
                       int* __restrict__ dstp, float* __restrict__ valp) {
  int e = blockIdx.x * 256 + threadIdx.x;
  int p = atomicAdd(&cur[src[e]], 1);
  dstp[p] = dst[e];
  valp[p] = ev[e];
}

// ---------------- fused dtype prep ----------------
// region 0: x -> xb (float4 chunks), region 1: W1^T, region 2: W2^T, region 3: W3^T
#define PREP_NX   (NN * FF / 4)
#define PREP_NW1  (FF * HD1)
#define PREP_NW23 (HD1 * HD2)

__global__ void k_prep(const float* __restrict__ x, unsigned short* __restrict__ xb,
                       const float* __restrict__ W1, unsigned short* __restrict__ W1t,
                       const float* __restrict__ W2, const float* __restrict__ W3,
                       unsigned short* __restrict__ W23t) {
  int gid = blockIdx.x * 256 + threadIdx.x;
  if (gid < PREP_NX) {
    float4 v = ((const float4*)x)[gid];
    ushort4 o;
    o.x = f2b(v.x); o.y = f2b(v.y); o.z = f2b(v.z); o.w = f2b(v.w);
    ((ushort4*)xb)[gid] = o;
    return;
  }
  int idx = gid - PREP_NX;
  if (idx < PREP_NW1) {                       // W1 [FF][HD1] -> W1t [HD1][FF]
    int k = idx / HD1, n = idx - k * HD1;
    W1t[(size_t)n * FF + k] = f2b(W1[idx]);
    return;
  }
  idx -= PREP_NW1;
  if (idx < PREP_NW23) {                      // W2 [HD1][HD2] -> W23t [0:HD2][HD1]
    int k = idx / HD2, n = idx - k * HD2;
    W23t[(size_t)n * HD1 + k] = f2b(W2[idx]);
    return;
  }
  idx -= PREP_NW23;
  if (idx < PREP_NW23) {                      // W3 -> W23t [HD2:2*HD2][HD1]
    int k = idx / HD2, n = idx - k * HD2;
    W23t[(size_t)(HD2 + n) * HD1 + k] = f2b(W3[idx]);
  }
}

// ---------------- GEMM: C[M,Nn] = A[M,K] * Bt[Nn,K]^T  (bf16 in, fp32 out) ----------------

__global__ __launch_bounds__(256) void gemm_bt(
    const unsigned short* __restrict__ A, const unsigned short* __restrict__ Bt,
    float* __restrict__ C, int Nn, int K) {
  int wave = threadIdx.x >> 6, lane = threadIdx.x & 63;
  int wr = wave >> 1, wc = wave & 1;
  int row0 = blockIdx.x * 128 + wr * 64;
  int col0 = blockIdx.y * 128 + wc * 64;
  int lm = lane & 31, lk = (lane >> 5) * 8;

  f32x16 acc[2][2] = {};
  const unsigned short* a0p = A + (size_t)(row0 + lm) * K + lk;
  const unsigned short* a1p = a0p + (size_t)32 * K;
  const unsigned short* b0p = Bt + (size_t)(col0 + lm) * K + lk;
  const unsigned short* b1p = b0p + (size_t)32 * K;

  for (int k0 = 0; k0 < K; k0 += 16) {
    bf16x8 a0 = ldb8(a0p + k0), a1 = ldb8(a1p + k0);
    bf16x8 b0 = ldb8(b0p + k0), b1 = ldb8(b1p + k0);
    acc[0][0] = mfma32(a0, b0, acc[0][0]);
    acc[0][1] = mfma32(a0, b1, acc[0][1]);
    acc[1][0] = mfma32(a1, b0, acc[1][0]);
    acc[1][1] = mfma32(a1, b1, acc[1][1]);
  }

#pragma unroll
  for (int ti = 0; ti < 2; ++ti)
#pragma unroll
    for (int tj = 0; tj < 2; ++tj)
#pragma unroll
      for (int r = 0; r < 16; ++r) {
        int row = row0 + ti * 32 + (r & 3) + 8 * (r >> 2) + 4 * (lane >> 5);
        int col = col0 + tj * 32 + lm;
        C[(size_t)row * Nn + col] = acc[ti][tj][r];
      }
}

// ---------------- SpMM (CSR gather, wave-per-node, float4, unrolled) ----------------

// h1b[i,:] = bf16(relu( sum_e val[e]*sup1[dst[e],:] )), D = 256
__global__ __launch_bounds__(256) void k_spmm_relu(
    const int* __restrict__ off, const int* __restrict__ dstp,
    const float* __restrict__ valp, const float* __restrict__ dense,
    unsigned short* __restrict__ outb) {
  int node = blockIdx.x * 4 + (threadIdx.x >> 6);
  int lane = threadIdx.x & 63;
  int l31 = lane & 31;
  int e0 = off[node];
  int e1 = (node == NN - 1) ? EE : off[node + 1];
  const float4* dp = (const float4*)dense;   // row = 64 float4
  float4 acc = make_float4(0.f, 0.f, 0.f, 0.f);
  int eb = e0;
  // full 32-edge batches: fixed trip count -> unrolled, loads pipelined
  for (; eb + 32 <= e1; eb += 32) {
    int dd = dstp[eb + l31];
    float vv = valp[eb + l31];
#pragma unroll
    for (int j = 0; j < 32; ++j) {
      int dj = __shfl(dd, j);
      float vj = __shfl(vv, j);
      float4 r = dp[(size_t)dj * 64 + lane];
      acc.x = fmaf(vj, r.x, acc.x);
      acc.y = fmaf(vj, r.y, acc.y);
      acc.z = fmaf(vj, r.z, acc.z);
      acc.w = fmaf(vj, r.w, acc.w);
    }
  }
  int rem = e1 - eb;
  if (rem > 0) {
    int dd = 0; float vv = 0.f;
    if (l31 < rem) { dd = dstp[eb + l31]; vv = valp[eb + l31]; }
    for (int j = 0; j < rem; ++j) {
      int dj = __shfl(dd, j);
      float vj = __shfl(vv, j);
      float4 r = dp[(size_t)dj * 64 + lane];
      acc.x = fmaf(vj, r.x, acc.x);
      acc.y = fmaf(vj, r.y, acc.y);
      acc.z = fmaf(vj, r.z, acc.z);
      acc.w = fmaf(vj, r.w, acc.w);
    }
  }
  ushort4 ob;
  ob.x = f2b(fmaxf(acc.x, 0.f));
  ob.y = f2b(fmaxf(acc.y, 0.f));
  ob.z = f2b(fmaxf(acc.z, 0.f));
  ob.w = f2b(fmaxf(acc.w, 0.f));
  ((ushort4*)outb)[(size_t)node * 64 + lane] = ob;
}

// mu/logvar from sup23 [N, 256]; fp32 to d_out tail + fused bf16 z (zb may be null)
__global__ __launch_bounds__(256) void k_spmm_mlv(
    const int* __restrict__ off, const int* __restrict__ dstp,
    const float* __restrict__ valp, const float* __restrict__ dense,
    float* __restrict__ mu, float* __restrict__ logvar,
    unsigned short* __restrict__ zb) {
  int node = blockIdx.x * 4 + (threadIdx.x >> 6);
  int lane = threadIdx.x & 63;
  int l31 = lane & 31;
  int e0 = off[node];
  int e1 = (node == NN - 1) ? EE : off[node + 1];
  const float4* dp = (const float4*)dense;   // row = 64 float4
  float4 acc = make_float4(0.f, 0.f, 0.f, 0.f);
  int eb = e0;
  for (; eb + 32 <= e1; eb += 32) {
    int dd = dstp[eb + l31];
    float vv = valp[eb + l31];
#pragma unroll
    for (int j = 0; j < 32; ++j) {
      int dj = __shfl(dd, j);
      float vj = __shfl(vv, j);
      float4 r = dp[(size_t)dj * 64 + lane];
      acc.x = fmaf(vj, r.x, acc.x);
      acc.y = fmaf(vj, r.y, acc.y);
      acc.z = fmaf(vj, r.z, acc.z);
      acc.w = fmaf(vj, r.w, acc.w);
    }
  }
  int rem = e1 - eb;
  if (rem > 0) {
    int dd = 0; float vv = 0.f;
    if (l31 < rem) { dd = dstp[eb + l31]; vv = valp[eb + l31]; }
    for (int j = 0; j < rem; ++j) {
      int dj = __shfl(dd, j);
      float vj = __shfl(vv, j);
      float4 r = dp[(size_t)dj * 64 + lane];
      acc.x = fmaf(vj, r.x, acc.x);
      acc.y = fmaf(vj, r.y, acc.y);
      acc.z = fmaf(vj, r.z, acc.z);
      acc.w = fmaf(vj, r.w, acc.w);
    }
  }
  // lanes 0..31 -> features 0..127 = mu (+ bf16 z); lanes 32..63 -> logvar
  if (lane < 32) {
    ((float4*)mu)[(size_t)node * 32 + lane] = acc;
    if (zb) {
      ushort4 ob;
      ob.x = f2b(acc.x); ob.y = f2b(acc.y); ob.z = f2b(acc.z); ob.w = f2b(acc.w);
      ((ushort4*)zb)[(size_t)node * 32 + lane] = ob;
    }
  } else {
    ((float4*)logvar)[(size_t)node * 32 + (lane - 32)] = acc;
  }
}

// ---------------- Decoder: out = sigmoid(Z * Z^T), Z = mu [NN, 128] ----------------

// bf16-Z variant (Z written into d_ws by k_spmm_mlv)
__global__ __launch_bounds__(256) void k_decoder_b(const unsigned short* __restrict__ Zb,
                                                   float* __restrict__ out) {
  int wave = threadIdx.x >> 6, lane = threadIdx.x & 63;
  int wr = wave >> 1, wc = wave & 1;
  int row0 = blockIdx.x * 128 + wr * 64;
  int col0 = blockIdx.y * 128 + wc * 64;
  int lm = lane & 31, lk = (lane >> 5) * 8;

  f32x16 acc[2][2] = {};
  const unsigned short* a0p = Zb + (size_t)(row0 + lm) * HD2 + lk;
  const unsigned short* a1p = a0p + (size_t)32 * HD2;
  const unsigned short* b0p = Zb + (size_t)(col0 + lm) * HD2 + lk;
  const unsigned short* b1p = b0p + (size_t)32 * HD2;

#pragma unroll
  for (int k0 = 0; k0 < HD2; k0 += 16) {
    bf16x8 a0 = ldb8(a0p + k0), a1 = ldb8(a1p + k0);
    bf16x8 b0 = ldb8(b0p + k0), b1 = ldb8(b1p + k0);
    acc[0][0] = mfma32(a0, b0, acc[0][0]);
    acc[0][1] = mfma32(a0, b1, acc[0][1]);
    acc[1][0] = mfma32(a1, b0, acc[1][0]);
    acc[1][1] = mfma32(a1, b1, acc[1][1]);
  }

#pragma unroll
  for (int ti = 0; ti < 2; ++ti)
#pragma unroll
    for (int tj = 0; tj < 2; ++tj)
#pragma unroll
      for (int r = 0; r < 16; ++r) {
        int row = row0 + ti * 32 + (r & 3) + 8 * (r >> 2) + 4 * (lane >> 5);
        int col = col0 + tj * 32 + lm;
        float s = sigmoid_fast(acc[ti][tj][r]);
        __builtin_nontemporal_store(s, &out[(size_t)row * NN + col]);
      }
}

// fp32-Z fallback when ws is too small for bf16 Z
__global__ __launch_bounds__(256) void k_decoder(const float* __restrict__ Zf,
                                                 float* __restrict__ out) {
  int wave = threadIdx.x >> 6, lane = threadIdx.x & 63;
  int wr = wave >> 1, wc = wave & 1;
  int row0 = blockIdx.x * 128 + wr * 64;
  int col0 = blockIdx.y * 128 + wc * 64;
  int lm = lane & 31, lk = (lane >> 5) * 8;

  f32x16 acc[2][2] = {};
  const float* a0p = Zf + (size_t)(row0 + lm) * HD2 + lk;
  const float* a1p = a0p + (size_t)32 * HD2;
  const float* b0p = Zf + (size_t)(col0 + lm) * HD2 + lk;
  const float* b1p = b0p + (size_t)32 * HD2;

#pragma unroll
  for (int k0 = 0; k0 < HD2; k0 += 16) {
    bf16x8 a0 = ldf8(a0p + k0), a1 = ldf8(a1p + k0);
    bf16x8 b0 = ldf8(b0p + k0), b1 = ldf8(b1p + k0);
    acc[0][0] = mfma32(a0, b0, acc[0][0]);
    acc[0][1] = mfma32(a0, b1, acc[0][1]);
    acc[1][0] = mfma32(a1, b0, acc[1][0]);
    acc[1][1] = mfma32(a1, b1, acc[1][1]);
  }

#pragma unroll
  for (int ti = 0; ti < 2; ++ti)
#pragma unroll
    for (int tj = 0; tj < 2; ++tj)
#pragma unroll
      for (int r = 0; r < 16; ++r) {
        int row = row0 + ti * 32 + (r & 3) + 8 * (r >> 2) + 4 * (lane >> 5);
        int col = col0 + tj * 32 + lm;
        float s = sigmoid_fast(acc[ti][tj][r]);
        __builtin_nontemporal_store(s, &out[(size_t)row * NN + col]);
      }
}

// ---------------- launch ----------------

extern "C" void kernel_launch(void* const* d_in, const int* in_sizes, int n_in,
                              void* d_out, int out_size, void* d_ws, size_t ws_size,
                              hipStream_t stream) {
  const float* x  = (const float*)d_in[0];
  const int*   src = (const int*)d_in[1];
  const int*   dst = (const int*)d_in[2];
  const float* ev  = (const float*)d_in[3];
  const float* W1  = (const float*)d_in[4];
  const float* W2  = (const float*)d_in[5];
  const float* W3  = (const float*)d_in[6];
  float* out = (float*)d_out;
  float* mu     = out + (size_t)NN * NN;
  float* logvar = mu + (size_t)NN * HD2;

  // Scratch lives inside out[0 : NN*NN] (604 MB; we need ~48 MB). Every
  // scratch byte is dead before the decoder overwrites the region.
  char* p = (char*)d_out;
  auto alloc = [&](size_t bytes) {
    char* r = p;
    p += (bytes + 255) & ~(size_t)255;
    return r;
  };
  unsigned short* xb   = (unsigned short*)alloc((size_t)NN * FF * 2);
  unsigned short* W1t  = (unsigned short*)alloc((size_t)HD1 * FF * 2);
  unsigned short* W23t = (unsigned short*)alloc((size_t)2 * HD2 * HD1 * 2);
  float*          sup1 = (float*)alloc((size_t)NN * HD1 * 4);
  unsigned short* h1b  = (unsigned short*)alloc((size_t)NN * HD1 * 2);
  float*         sup23 = (float*)alloc((size_t)NN * 2 * HD2 * 4);
  int* deg  = (int*)alloc(NN * 4);
  int* off  = (int*)alloc(NN * 4);
  int* cur  = (int*)alloc(NN * 4);
  int*   dstp = (int*)alloc((size_t)EE * 4);
  float* valp = (float*)alloc((size_t)EE * 4);
  int*   bsum = (int*)alloc((NN / 256) * 4);

  // bf16 Z for the decoder goes into d_ws iff it fits (3.15 MB); it must
  // NOT live in out[0:NN*NN] (the decoder overwrites that region while
  // other blocks still read Z).
  const size_t zb_bytes = (size_t)NN * HD2 * 2;
  bool use_zb = (d_ws != nullptr) && (ws_size >= zb_bytes + 256);
  unsigned short* zb = use_zb ? (unsigned short*)d_ws : nullptr;

  // CSR build on src (permuting dst/val into CSR order)
  hipMemsetAsync(deg, 0, NN * 4, stream);
  k_hist<<<EE / 256, 256, 0, stream>>>(src, deg);
  k_scan1<<<NN / 256, 256, 0, stream>>>(deg, off, bsum);
  k_scan2<<<1, 64, 0, stream>>>(bsum);
  k_scan3<<<NN / 256, 256, 0, stream>>>(bsum, off, cur);
  k_fill<<<EE / 256, 256, 0, stream>>>(src, dst, ev, cur, dstp, valp);

  // fused dtype prep (x->bf16, W1^T, W2^T, W3^T)
  {
    int total = PREP_NX + PREP_NW1 + 2 * PREP_NW23;
    k_prep<<<(total + 255) / 256, 256, 0, stream>>>(x, xb, W1, W1t, W2, W3, W23t);
  }

  // encoder layer 1: sup1 = x @ W1 ; h1 = relu(spmm(sup1))
  gemm_bt<<<dim3(NN / 128, HD1 / 128), 256, 0, stream>>>(xb, W1t, sup1, HD1, FF);
  k_spmm_relu<<<NN / 4, 256, 0, stream>>>(off, dstp, valp, sup1, h1b);

  // encoder layer 2 (mu|logvar fused): sup23 = h1 @ [W2|W3] ; spmm -> mu,logvar,zb
  gemm_bt<<<dim3(NN / 128, (2 * HD2) / 128), 256, 0, stream>>>(h1b, W23t, sup23, 2 * HD2, HD1);
  k_spmm_mlv<<<NN / 4, 256, 0, stream>>>(off, dstp, valp, sup23, mu, logvar, zb);

  // decoder: out[0 : NN*NN] = sigmoid(mu @ mu^T)  (z = mu in eval mode)
  if (use_zb) {
    k_decoder_b<<<dim3(NN / 128, NN / 128), 256, 0, stream>>>(zb, out);
  } else {
    k_decoder<<<dim3(NN / 128, NN / 128), 256, 0, stream>>>(mu, out);
  }
}

// Round 3
// 795.014 us; speedup vs baseline: 1.5304x; 1.0629x over previous
//
#include <hip/hip_runtime.h>
#include <stdint.h>

// Round 6:
//  - Decoder Z pre-swizzled into MFMA-fragment-major layout zf[R][C][lane][8]
//    (tiny k_zf kernel): every decoder fragment load becomes a fully
//    coalesced 1KB request (was 32 cachelines/inst -> ~61us of TA
//    serialization vs the ~97us HBM write drain).
//  - SpMM is linear => commutes with the weight GEMM. Layer 2 is now
//    SpMM-first: aggh = spmm(h1b) gathering 512B bf16 rows (was 1KB fp32
//    rows of sup23), then gemm_mlv -> mu/logvar directly; sup23 eliminated.
//  - Layer 1: sup1 stored bf16, halving its gather volume too. One shared
//    templated SpMM kernel (RELU flag).
//  - gemm_mlv epilogue writes mu (by==0) / logvar (by==1) directly.

#define NN 12288   // nodes
#define FF 512     // input feature dim
#define HD1 256    // hidden 1
#define HD2 128    // latent
#define EE 393216  // edges  (EE % 256 == 0)

typedef short bf16x8 __attribute__((ext_vector_type(8)));   // 8 bf16 in 4 VGPRs
typedef float f32x16 __attribute__((ext_vector_type(16)));

__device__ inline unsigned short f2b(float f) {
  // fp32 -> bf16 round-to-nearest-even (inputs finite)
  unsigned int u = __float_as_uint(f);
  unsigned int r = u + 0x7fffu + ((u >> 16) & 1u);
  return (unsigned short)(r >> 16);
}

__device__ inline float b2f(unsigned short u) {
  return __uint_as_float((unsigned int)u << 16);
}

__device__ inline bf16x8 ldb8(const unsigned short* p) {
  return *(const bf16x8*)p;
}

// load 8 fp32, convert to bf16 fragment
__device__ inline bf16x8 ldf8(const float* p) {
  float4 v0 = ((const float4*)p)[0];
  float4 v1 = ((const float4*)p)[1];
  bf16x8 r;
  r[0] = (short)f2b(v0.x); r[1] = (short)f2b(v0.y);
  r[2] = (short)f2b(v0.z); r[3] = (short)f2b(v0.w);
  r[4] = (short)f2b(v1.x); r[5] = (short)f2b(v1.y);
  r[6] = (short)f2b(v1.z); r[7] = (short)f2b(v1.w);
  return r;
}

__device__ inline f32x16 mfma32(bf16x8 a, bf16x8 b, f32x16 c) {
  return __builtin_amdgcn_mfma_f32_32x32x16_bf16(a, b, c, 0, 0, 0);
}

__device__ inline float sigmoid_fast(float v) {
  return __builtin_amdgcn_rcpf(1.0f + __expf(-v));   // v_rcp_f32: 1 ulp
}

// ---------------- CSR build ----------------

__global__ void k_hist(const int* __restrict__ src, int* __restrict__ deg) {
  int e = blockIdx.x * 256 + threadIdx.x;   // EE multiple of 256
  atomicAdd(&deg[src[e]], 1);
}

// stage 1: per-256-chunk exclusive scan + chunk total
__global__ void k_scan1(const int* __restrict__ deg, int* __restrict__ off,
                        int* __restrict__ bsum) {
  __shared__ int sdata[256];
  int t = threadIdx.x;
  int i = blockIdx.x * 256 + t;
  int v = deg[i];
  sdata[t] = v;
  __syncthreads();
  for (int s = 1; s < 256; s <<= 1) {
    int u = (t >= s) ? sdata[t - s] : 0;
    __syncthreads();
    sdata[t] += u;
    __syncthreads();
  }
  off[i] = sdata[t] - v;                 // exclusive within chunk
  if (t == 255) bsum[blockIdx.x] = sdata[255];
}

// stage 2: one wave scans the 48 chunk totals -> exclusive chunk offsets
__global__ void k_scan2(int* __restrict__ bsum) {
  int t = threadIdx.x;                   // 64 threads
  int orig = (t < NN / 256) ? bsum[t] : 0;
  int v = orig;
  for (int s = 1; s < 64; s <<= 1) {
    int u = __shfl_up(v, s);
    if (t >= s) v += u;
  }
  if (t < NN / 256) bsum[t] = v - orig;  // exclusive
}

// stage 3: add chunk offsets, init cur
__global__ void k_scan3(const int* __restrict__ bsum, int* __restrict__ off,
                        int* __restrict__ cur) {
  int i = blockIdx.x * 256 + threadIdx.x;
  int o = off[i] + bsum[blockIdx.x];
  off[i] = o;
  cur[i] = o;
}

// permute (dst, val) into CSR order -> contiguous metadata for the SpMMs
__global__ void k_fill(const int* __restrict__ src, const int* __restrict__ dst,
                       const float* __restrict__ ev, int* __restrict__ cur,
                       int* __restrict__ dstp, float* __restrict__ valp) {
  int e = blockIdx.x * 256 + threadIdx.x;
  int p = atomicAdd(&cur[src[e]], 1);
  dstp[p] = dst[e];
  valp[p] = ev[e];
}

// ---------------- fused dtype prep ----------------
#define PREP_NX   (NN * FF / 4)
#define PREP_NW1  (FF * HD1)
#define PREP_NW23 (HD1 * HD2)

__global__ void k_prep(const float* __restrict__ x, unsigned short* __restrict__ xb,
                       const float* __restrict__ W1, unsigned short* __restrict__ W1t,
                       const float* __restrict__ W2, const float* __restrict__ W3,
                       unsigned short* __restrict__ W23t) {
  int gid = blockIdx.x * 256 + threadIdx.x;
  if (gid < PREP_NX) {
    float4 v = ((const float4*)x)[gid];
    ushort4 o;
    o.x = f2b(v.x); o.y = f2b(v.y); o.z = f2b(v.z); o.w = f2b(v.w);
    ((ushort4*)xb)[gid] = o;
    return;
  }
  int idx = gid - PREP_NX;
  if (idx < PREP_NW1) {                       // W1 [FF][HD1] -> W1t [HD1][FF]
    int k = idx / HD1, n = idx - k * HD1;
    W1t[(size_t)n * FF + k] = f2b(W1[idx]);
    return;
  }
  idx -= PREP_NW1;
  if (idx < PREP_NW23) {                      // W2 [HD1][HD2] -> W23t [0:HD2][HD1]
    int k = idx / HD2, n = idx - k * HD2;
    W23t[(size_t)n * HD1 + k] = f2b(W2[idx]);
    return;
  }
  idx -= PREP_NW23;
  if (idx < PREP_NW23) {                      // W3 -> W23t [HD2:2*HD2][HD1]
    int k = idx / HD2, n = idx - k * HD2;
    W23t[(size_t)(HD2 + n) * HD1 + k] = f2b(W3[idx]);
  }
}

// ---------------- GEMM: C[M,Nn] = A[M,K] * Bt[Nn,K]^T, bf16 out ----------------

__global__ __launch_bounds__(256) void gemm_btb(
    const unsigned short* __restrict__ A, const unsigned short* __restrict__ Bt,
    unsigned short* __restrict__ C, int Nn, int K) {
  int wave = threadIdx.x >> 6, lane = threadIdx.x & 63;
  int wr = wave >> 1, wc = wave & 1;
  int row0 = blockIdx.x * 128 + wr * 64;
  int col0 = blockIdx.y * 128 + wc * 64;
  int lm = lane & 31, lk = (lane >> 5) * 8;

  f32x16 acc[2][2] = {};
  const unsigned short* a0p = A + (size_t)(row0 + lm) * K + lk;
  const unsigned short* a1p = a0p + (size_t)32 * K;
  const unsigned short* b0p = Bt + (size_t)(col0 + lm) * K + lk;
  const unsigned short* b1p = b0p + (size_t)32 * K;

  for (int k0 = 0; k0 < K; k0 += 16) {
    bf16x8 a0 = ldb8(a0p + k0), a1 = ldb8(a1p + k0);
    bf16x8 b0 = ldb8(b0p + k0), b1 = ldb8(b1p + k0);
    acc[0][0] = mfma32(a0, b0, acc[0][0]);
    acc[0][1] = mfma32(a0, b1, acc[0][1]);
    acc[1][0] = mfma32(a1, b0, acc[1][0]);
    acc[1][1] = mfma32(a1, b1, acc[1][1]);
  }

#pragma unroll
  for (int ti = 0; ti < 2; ++ti)
#pragma unroll
    for (int tj = 0; tj < 2; ++tj)
#pragma unroll
      for (int r = 0; r < 16; ++r) {
        int row = row0 + ti * 32 + (r & 3) + 8 * (r >> 2) + 4 * (lane >> 5);
        int col = col0 + tj * 32 + lm;
        C[(size_t)row * Nn + col] = f2b(acc[ti][tj][r]);
      }
}

// GEMM for layer 2: A[N,256] bf16 (aggh), Bt = W23t [256][256].
// by==0 -> cols 0..127 = mu, by==1 -> cols 128..255 = logvar. fp32 out.
__global__ __launch_bounds__(256) void gemm_mlv(
    const unsigned short* __restrict__ A, const unsigned short* __restrict__ Bt,
    float* __restrict__ mu, float* __restrict__ logvar) {
  int wave = threadIdx.x >> 6, lane = threadIdx.x & 63;
  int wr = wave >> 1, wc = wave & 1;
  int row0 = blockIdx.x * 128 + wr * 64;
  int colg0 = blockIdx.y * 128 + wc * 64;   // global col (B row)
  int lm = lane & 31, lk = (lane >> 5) * 8;
  const int K = HD1;

  f32x16 acc[2][2] = {};
  const unsigned short* a0p = A + (size_t)(row0 + lm) * K + lk;
  const unsigned short* a1p = a0p + (size_t)32 * K;
  const unsigned short* b0p = Bt + (size_t)(colg0 + lm) * K + lk;
  const unsigned short* b1p = b0p + (size_t)32 * K;

#pragma unroll
  for (int k0 = 0; k0 < K; k0 += 16) {
    bf16x8 a0 = ldb8(a0p + k0), a1 = ldb8(a1p + k0);
    bf16x8 b0 = ldb8(b0p + k0), b1 = ldb8(b1p + k0);
    acc[0][0] = mfma32(a0, b0, acc[0][0]);
    acc[0][1] = mfma32(a0, b1, acc[0][1]);
    acc[1][0] = mfma32(a1, b0, acc[1][0]);
    acc[1][1] = mfma32(a1, b1, acc[1][1]);
  }

  float* Cout = (blockIdx.y == 0) ? mu : logvar;
  int coll0 = wc * 64;                      // local col in [0,128)
#pragma unroll
  for (int ti = 0; ti < 2; ++ti)
#pragma unroll
    for (int tj = 0; tj < 2; ++tj)
#pragma unroll
      for (int r = 0; r < 16; ++r) {
        int row = row0 + ti * 32 + (r & 3) + 8 * (r >> 2) + 4 * (lane >> 5);
        int col = coll0 + tj * 32 + lm;
        Cout[(size_t)row * HD2 + col] = acc[ti][tj][r];
      }
}

// ---------------- SpMM (CSR gather, wave-per-node, bf16 rows 512B) ----------------
// out[i,:] = bf16( maybe_relu( sum_e val[e]*dense[dst[e],:] ) ), D = 256 bf16

template <int RELU>
__global__ __launch_bounds__(256) void k_spmm_b(
    const int* __restrict__ off, const int* __restrict__ dstp,
    const float* __restrict__ valp, const unsigned short* __restrict__ dense,
    unsigned short* __restrict__ outb) {
  int node = blockIdx.x * 4 + (threadIdx.x >> 6);
  int lane = threadIdx.x & 63;
  int l31 = lane & 31;
  int e0 = off[node];
  int e1 = (node == NN - 1) ? EE : off[node + 1];
  const ushort4* dp = (const ushort4*)dense;   // row = 64 ushort4 (512B)
  float a0 = 0.f, a1 = 0.f, a2 = 0.f, a3 = 0.f;
  int eb = e0;
  for (; eb + 32 <= e1; eb += 32) {
    int dd = dstp[eb + l31];
    float vv = valp[eb + l31];
#pragma unroll
    for (int j = 0; j < 32; ++j) {
      int dj = __shfl(dd, j);
      float vj = __shfl(vv, j);
      ushort4 r = dp[(size_t)dj * 64 + lane];
      a0 = fmaf(vj, b2f(r.x), a0);
      a1 = fmaf(vj, b2f(r.y), a1);
      a2 = fmaf(vj, b2f(r.z), a2);
      a3 = fmaf(vj, b2f(r.w), a3);
    }
  }
  int rem = e1 - eb;
  if (rem > 0) {
    int dd = 0; float vv = 0.f;
    if (l31 < rem) { dd = dstp[eb + l31]; vv = valp[eb + l31]; }
    for (int j = 0; j < rem; ++j) {
      int dj = __shfl(dd, j);
      float vj = __shfl(vv, j);
      ushort4 r = dp[(size_t)dj * 64 + lane];
      a0 = fmaf(vj, b2f(r.x), a0);
      a1 = fmaf(vj, b2f(r.y), a1);
      a2 = fmaf(vj, b2f(r.z), a2);
      a3 = fmaf(vj, b2f(r.w), a3);
    }
  }
  if (RELU) {
    a0 = fmaxf(a0, 0.f); a1 = fmaxf(a1, 0.f);
    a2 = fmaxf(a2, 0.f); a3 = fmaxf(a3, 0.f);
  }
  ushort4 ob;
  ob.x = f2b(a0); ob.y = f2b(a1); ob.z = f2b(a2); ob.w = f2b(a3);
  ((ushort4*)outb)[(size_t)node * 64 + lane] = ob;
}

// ---------------- Z fragment swizzle ----------------
// zf chunk t (8 bf16, 16B): t = (R*8 + C)*64 + lane;
// element j of chunk = Z[R*32 + (lane&31)][C*16 + (lane>>5)*8 + j]
__global__ void k_zf(const float* __restrict__ mu, unsigned short* __restrict__ zf) {
  int t = blockIdx.x * 256 + threadIdx.x;      // t < NN*HD2/8 = 196608
  int lane = t & 63;
  int C = (t >> 6) & 7;
  int R = t >> 9;
  int srow = R * 32 + (lane & 31);
  int scol = C * 16 + (lane >> 5) * 8;
  const float* s = mu + (size_t)srow * HD2 + scol;
  float4 v0 = ((const float4*)s)[0];
  float4 v1 = ((const float4*)s)[1];
  ushort4 o0, o1;
  o0.x = f2b(v0.x); o0.y = f2b(v0.y); o0.z = f2b(v0.z); o0.w = f2b(v0.w);
  o1.x = f2b(v1.x); o1.y = f2b(v1.y); o1.z = f2b(v1.z); o1.w = f2b(v1.w);
  ((ushort4*)zf)[2 * t]     = o0;
  ((ushort4*)zf)[2 * t + 1] = o1;
}

// ---------------- Decoder: out = sigmoid(Z * Z^T) ----------------

// fragment-major zf variant: every load is a coalesced 1KB request
__global__ __launch_bounds__(256) void k_decoder_z(const unsigned short* __restrict__ zf,
                                                   float* __restrict__ out) {
  int wave = threadIdx.x >> 6, lane = threadIdx.x & 63;
  int wr = wave >> 1, wc = wave & 1;
  int row0 = blockIdx.x * 128 + wr * 64;
  int col0 = blockIdx.y * 128 + wc * 64;
  int lm = lane & 31;
  int aR = row0 >> 5;
  int bR = col0 >> 5;
  const unsigned short* ap = zf + ((size_t)aR * 8 * 64 + lane) * 8;
  const unsigned short* bp = zf + ((size_t)bR * 8 * 64 + lane) * 8;

  f32x16 acc[2][2] = {};
#pragma unroll
  for (int C = 0; C < 8; ++C) {
    bf16x8 a0 = ldb8(ap + C * 512);
    bf16x8 a1 = ldb8(ap + 4096 + C * 512);
    bf16x8 b0 = ldb8(bp + C * 512);
    bf16x8 b1 = ldb8(bp + 4096 + C * 512);
    acc[0][0] = mfma32(a0, b0, acc[0][0]);
    acc[0][1] = mfma32(a0, b1, acc[0][1]);
    acc[1][0] = mfma32(a1, b0, acc[1][0]);
    acc[1][1] = mfma32(a1, b1, acc[1][1]);
  }

#pragma unroll
  for (int ti = 0; ti < 2; ++ti)
#pragma unroll
    for (int tj = 0; tj < 2; ++tj)
#pragma unroll
      for (int r = 0; r < 16; ++r) {
        int row = row0 + ti * 32 + (r & 3) + 8 * (r >> 2) + 4 * (lane >> 5);
        int col = col0 + tj * 32 + lm;
        float s = sigmoid_fast(acc[ti][tj][r]);
        __builtin_nontemporal_store(s, &out[(size_t)row * NN + col]);
      }
}

// fp32-Z fallback when ws is too small for zf
__global__ __launch_bounds__(256) void k_decoder(const float* __restrict__ Zf,
                                                 float* __restrict__ out) {
  int wave = threadIdx.x >> 6, lane = threadIdx.x & 63;
  int wr = wave >> 1, wc = wave & 1;
  int row0 = blockIdx.x * 128 + wr * 64;
  int col0 = blockIdx.y * 128 + wc * 64;
  int lm = lane & 31, lk = (lane >> 5) * 8;

  f32x16 acc[2][2] = {};
  const float* a0p = Zf + (size_t)(row0 + lm) * HD2 + lk;
  const float* a1p = a0p + (size_t)32 * HD2;
  const float* b0p = Zf + (size_t)(col0 + lm) * HD2 + lk;
  const float* b1p = b0p + (size_t)32 * HD2;

#pragma unroll
  for (int k0 = 0; k0 < HD2; k0 += 16) {
    bf16x8 a0 = ldf8(a0p + k0), a1 = ldf8(a1p + k0);
    bf16x8 b0 = ldf8(b0p + k0), b1 = ldf8(b1p + k0);
    acc[0][0] = mfma32(a0, b0, acc[0][0]);
    acc[0][1] = mfma32(a0, b1, acc[0][1]);
    acc[1][0] = mfma32(a1, b0, acc[1][0]);
    acc[1][1] = mfma32(a1, b1, acc[1][1]);
  }

#pragma unroll
  for (int ti = 0; ti < 2; ++ti)
#pragma unroll
    for (int tj = 0; tj < 2; ++tj)
#pragma unroll
      for (int r = 0; r < 16; ++r) {
        int row = row0 + ti * 32 + (r & 3) + 8 * (r >> 2) + 4 * (lane >> 5);
        int col = col0 + tj * 32 + lm;
        float s = sigmoid_fast(acc[ti][tj][r]);
        __builtin_nontemporal_store(s, &out[(size_t)row * NN + col]);
      }
}

// ---------------- launch ----------------

extern "C" void kernel_launch(void* const* d_in, const int* in_sizes, int n_in,
                              void* d_out, int out_size, void* d_ws, size_t ws_size,
                              hipStream_t stream) {
  const float* x  = (const float*)d_in[0];
  const int*   src = (const int*)d_in[1];
  const int*   dst = (const int*)d_in[2];
  const float* ev  = (const float*)d_in[3];
  const float* W1  = (const float*)d_in[4];
  const float* W2  = (const float*)d_in[5];
  const float* W3  = (const float*)d_in[6];
  float* out = (float*)d_out;
  float* mu     = out + (size_t)NN * NN;
  float* logvar = mu + (size_t)NN * HD2;

  // Scratch lives inside out[0 : NN*NN] (604 MB; we need ~40 MB). Every
  // scratch byte is dead before the decoder overwrites the region.
  char* p = (char*)d_out;
  auto alloc = [&](size_t bytes) {
    char* r = p;
    p += (bytes + 255) & ~(size_t)255;
    return r;
  };
  unsigned short* xb    = (unsigned short*)alloc((size_t)NN * FF * 2);
  unsigned short* W1t   = (unsigned short*)alloc((size_t)HD1 * FF * 2);
  unsigned short* W23t  = (unsigned short*)alloc((size_t)2 * HD2 * HD1 * 2);
  unsigned short* sup1b = (unsigned short*)alloc((size_t)NN * HD1 * 2);
  unsigned short* h1b   = (unsigned short*)alloc((size_t)NN * HD1 * 2);
  unsigned short* aggh  = (unsigned short*)alloc((size_t)NN * HD1 * 2);
  int* deg  = (int*)alloc(NN * 4);
  int* off  = (int*)alloc(NN * 4);
  int* cur  = (int*)alloc(NN * 4);
  int*   dstp = (int*)alloc((size_t)EE * 4);
  float* valp = (float*)alloc((size_t)EE * 4);
  int*   bsum = (int*)alloc((NN / 256) * 4);

  // fragment-major bf16 Z in d_ws (3.15 MB); must NOT live inside
  // out[0:NN*NN] (decoder overwrites that region while blocks still read Z).
  const size_t zf_bytes = (size_t)NN * HD2 * 2;
  bool use_zf = (d_ws != nullptr) && (ws_size >= zf_bytes + 256);
  unsigned short* zf = (unsigned short*)d_ws;

  // CSR build on src (permuting dst/val into CSR order)
  hipMemsetAsync(deg, 0, NN * 4, stream);
  k_hist<<<EE / 256, 256, 0, stream>>>(src, deg);
  k_scan1<<<NN / 256, 256, 0, stream>>>(deg, off, bsum);
  k_scan2<<<1, 64, 0, stream>>>(bsum);
  k_scan3<<<NN / 256, 256, 0, stream>>>(bsum, off, cur);
  k_fill<<<EE / 256, 256, 0, stream>>>(src, dst, ev, cur, dstp, valp);

  // fused dtype prep (x->bf16, W1^T, W2^T, W3^T)
  {
    int total = PREP_NX + PREP_NW1 + 2 * PREP_NW23;
    k_prep<<<(total + 255) / 256, 256, 0, stream>>>(x, xb, W1, W1t, W2, W3, W23t);
  }

  // encoder layer 1: sup1b = bf16(x @ W1) ; h1b = bf16(relu(spmm(sup1b)))
  gemm_btb<<<dim3(NN / 128, HD1 / 128), 256, 0, stream>>>(xb, W1t, sup1b, HD1, FF);
  k_spmm_b<1><<<NN / 4, 256, 0, stream>>>(off, dstp, valp, sup1b, h1b);

  // encoder layer 2 (SpMM-first; spmm commutes with @W):
  // aggh = bf16(spmm(h1b)) ; [mu|logvar] = aggh @ [W2|W3]
  k_spmm_b<0><<<NN / 4, 256, 0, stream>>>(off, dstp, valp, h1b, aggh);
  gemm_mlv<<<dim3(NN / 128, 2), 256, 0, stream>>>(aggh, W23t, mu, logvar);

  // decoder: out[0 : NN*NN] = sigmoid(z z^T), z = mu (eval mode)
  if (use_zf) {
    k_zf<<<(NN * HD2 / 8) / 256, 256, 0, stream>>>(mu, zf);
    k_decoder_z<<<dim3(NN / 128, NN / 128), 256, 0, stream>>>(zf, out);
  } else {
    k_decoder<<<dim3(NN / 128, NN / 128), 256, 0, stream>>>(mu, out);
  }
}

// Round 4
// 789.446 us; speedup vs baseline: 1.5412x; 1.0071x over previous
//
#include <hip/hip_runtime.h>
#include <stdint.h>

// Round 7:
//  - Decoder: 128x256 tile, 512 threads (8 waves = 2x4 of 64x64): halves
//    block count (9216->4608) and fragment-read traffic (590->442 MB).
//  - GEMMs: compile-time K (template), unroll-4 K-loop -- the 192-block
//    layer-1 GEMM has ~1 wave/SIMD so ILP must come from unrolling.
//  - k_hist fused into k_prep (independent input-only work, one launch).
//  - Everything else carried from R6 (SpMM-first layer 2, bf16 gathers,
//    fragment-major zf decoder input, nt stores, fast sigmoid).

#define NN 12288   // nodes
#define FF 512     // input feature dim
#define HD1 256    // hidden 1
#define HD2 128    // latent
#define EE 393216  // edges  (EE % 256 == 0)

typedef short bf16x8 __attribute__((ext_vector_type(8)));   // 8 bf16 in 4 VGPRs
typedef float f32x16 __attribute__((ext_vector_type(16)));

__device__ inline unsigned short f2b(float f) {
  // fp32 -> bf16 round-to-nearest-even (inputs finite)
  unsigned int u = __float_as_uint(f);
  unsigned int r = u + 0x7fffu + ((u >> 16) & 1u);
  return (unsigned short)(r >> 16);
}

__device__ inline float b2f(unsigned short u) {
  return __uint_as_float((unsigned int)u << 16);
}

__device__ inline bf16x8 ldb8(const unsigned short* p) {
  return *(const bf16x8*)p;
}

// load 8 fp32, convert to bf16 fragment
__device__ inline bf16x8 ldf8(const float* p) {
  float4 v0 = ((const float4*)p)[0];
  float4 v1 = ((const float4*)p)[1];
  bf16x8 r;
  r[0] = (short)f2b(v0.x); r[1] = (short)f2b(v0.y);
  r[2] = (short)f2b(v0.z); r[3] = (short)f2b(v0.w);
  r[4] = (short)f2b(v1.x); r[5] = (short)f2b(v1.y);
  r[6] = (short)f2b(v1.z); r[7] = (short)f2b(v1.w);
  return r;
}

__device__ inline f32x16 mfma32(bf16x8 a, bf16x8 b, f32x16 c) {
  return __builtin_amdgcn_mfma_f32_32x32x16_bf16(a, b, c, 0, 0, 0);
}

__device__ inline float sigmoid_fast(float v) {
  return __builtin_amdgcn_rcpf(1.0f + __expf(-v));   // v_rcp_f32: 1 ulp
}

// ---------------- fused hist + dtype prep ----------------
#define HIST_NB   (EE / 256)
#define PREP_NX   (NN * FF / 4)
#define PREP_NW1  (FF * HD1)
#define PREP_NW23 (HD1 * HD2)

__global__ void k_hist_prep(const int* __restrict__ src, int* __restrict__ deg,
                            const float* __restrict__ x, unsigned short* __restrict__ xb,
                            const float* __restrict__ W1, unsigned short* __restrict__ W1t,
                            const float* __restrict__ W2, const float* __restrict__ W3,
                            unsigned short* __restrict__ W23t) {
  if (blockIdx.x < HIST_NB) {
    int e = blockIdx.x * 256 + threadIdx.x;
    atomicAdd(&deg[src[e]], 1);
    return;
  }
  int gid = (blockIdx.x - HIST_NB) * 256 + threadIdx.x;
  if (gid < PREP_NX) {
    float4 v = ((const float4*)x)[gid];
    ushort4 o;
    o.x = f2b(v.x); o.y = f2b(v.y); o.z = f2b(v.z); o.w = f2b(v.w);
    ((ushort4*)xb)[gid] = o;
    return;
  }
  int idx = gid - PREP_NX;
  if (idx < PREP_NW1) {                       // W1 [FF][HD1] -> W1t [HD1][FF]
    int k = idx / HD1, n = idx - k * HD1;
    W1t[(size_t)n * FF + k] = f2b(W1[idx]);
    return;
  }
  idx -= PREP_NW1;
  if (idx < PREP_NW23) {                      // W2 [HD1][HD2] -> W23t [0:HD2][HD1]
    int k = idx / HD2, n = idx - k * HD2;
    W23t[(size_t)n * HD1 + k] = f2b(W2[idx]);
    return;
  }
  idx -= PREP_NW23;
  if (idx < PREP_NW23) {                      // W3 -> W23t [HD2:2*HD2][HD1]
    int k = idx / HD2, n = idx - k * HD2;
    W23t[(size_t)(HD2 + n) * HD1 + k] = f2b(W3[idx]);
  }
}

// ---------------- CSR build ----------------

// stage 1: per-256-chunk exclusive scan + chunk total
__global__ void k_scan1(const int* __restrict__ deg, int* __restrict__ off,
                        int* __restrict__ bsum) {
  __shared__ int sdata[256];
  int t = threadIdx.x;
  int i = blockIdx.x * 256 + t;
  int v = deg[i];
  sdata[t] = v;
  __syncthreads();
  for (int s = 1; s < 256; s <<= 1) {
    int u = (t >= s) ? sdata[t - s] : 0;
    __syncthreads();
    sdata[t] += u;
    __syncthreads();
  }
  off[i] = sdata[t] - v;                 // exclusive within chunk
  if (t == 255) bsum[blockIdx.x] = sdata[255];
}

// stage 2: one wave scans the 48 chunk totals -> exclusive chunk offsets
__global__ void k_scan2(int* __restrict__ bsum) {
  int t = threadIdx.x;                   // 64 threads
  int orig = (t < NN / 256) ? bsum[t] : 0;
  int v = orig;
  for (int s = 1; s < 64; s <<= 1) {
    int u = __shfl_up(v, s);
    if (t >= s) v += u;
  }
  if (t < NN / 256) bsum[t] = v - orig;  // exclusive
}

// stage 3: add chunk offsets, init cur
__global__ void k_scan3(const int* __restrict__ bsum, int* __restrict__ off,
                        int* __restrict__ cur) {
  int i = blockIdx.x * 256 + threadIdx.x;
  int o = off[i] + bsum[blockIdx.x];
  off[i] = o;
  cur[i] = o;
}

// permute (dst, val) into CSR order -> contiguous metadata for the SpMMs
__global__ void k_fill(const int* __restrict__ src, const int* __restrict__ dst,
                       const float* __restrict__ ev, int* __restrict__ cur,
                       int* __restrict__ dstp, float* __restrict__ valp) {
  int e = blockIdx.x * 256 + threadIdx.x;
  int p = atomicAdd(&cur[src[e]], 1);
  dstp[p] = dst[e];
  valp[p] = ev[e];
}

// ---------------- GEMM: C[M,Nn] = A[M,K] * Bt[Nn,K]^T, bf16 out ----------------

template <int K>
__global__ __launch_bounds__(256) void gemm_btb(
    const unsigned short* __restrict__ A, const unsigned short* __restrict__ Bt,
    unsigned short* __restrict__ C, int Nn) {
  int wave = threadIdx.x >> 6, lane = threadIdx.x & 63;
  int wr = wave >> 1, wc = wave & 1;
  int row0 = blockIdx.x * 128 + wr * 64;
  int col0 = blockIdx.y * 128 + wc * 64;
  int lm = lane & 31, lk = (lane >> 5) * 8;

  f32x16 acc[2][2] = {};
  const unsigned short* a0p = A + (size_t)(row0 + lm) * K + lk;
  const unsigned short* a1p = a0p + (size_t)32 * K;
  const unsigned short* b0p = Bt + (size_t)(col0 + lm) * K + lk;
  const unsigned short* b1p = b0p + (size_t)32 * K;

#pragma unroll 4
  for (int k0 = 0; k0 < K; k0 += 16) {
    bf16x8 a0 = ldb8(a0p + k0), a1 = ldb8(a1p + k0);
    bf16x8 b0 = ldb8(b0p + k0), b1 = ldb8(b1p + k0);
    acc[0][0] = mfma32(a0, b0, acc[0][0]);
    acc[0][1] = mfma32(a0, b1, acc[0][1]);
    acc[1][0] = mfma32(a1, b0, acc[1][0]);
    acc[1][1] = mfma32(a1, b1, acc[1][1]);
  }

#pragma unroll
  for (int ti = 0; ti < 2; ++ti)
#pragma unroll
    for (int tj = 0; tj < 2; ++tj)
#pragma unroll
      for (int r = 0; r < 16; ++r) {
        int row = row0 + ti * 32 + (r & 3) + 8 * (r >> 2) + 4 * (lane >> 5);
        int col = col0 + tj * 32 + lm;
        C[(size_t)row * Nn + col] = f2b(acc[ti][tj][r]);
      }
}

// GEMM for layer 2: A[N,256] bf16 (aggh), Bt = W23t [256][256].
// by==0 -> cols 0..127 = mu, by==1 -> cols 128..255 = logvar. fp32 out.
__global__ __launch_bounds__(256) void gemm_mlv(
    const unsigned short* __restrict__ A, const unsigned short* __restrict__ Bt,
    float* __restrict__ mu, float* __restrict__ logvar) {
  int wave = threadIdx.x >> 6, lane = threadIdx.x & 63;
  int wr = wave >> 1, wc = wave & 1;
  int row0 = blockIdx.x * 128 + wr * 64;
  int colg0 = blockIdx.y * 128 + wc * 64;   // global col (B row)
  int lm = lane & 31, lk = (lane >> 5) * 8;
  const int K = HD1;

  f32x16 acc[2][2] = {};
  const unsigned short* a0p = A + (size_t)(row0 + lm) * K + lk;
  const unsigned short* a1p = a0p + (size_t)32 * K;
  const unsigned short* b0p = Bt + (size_t)(colg0 + lm) * K + lk;
  const unsigned short* b1p = b0p + (size_t)32 * K;

#pragma unroll 4
  for (int k0 = 0; k0 < K; k0 += 16) {
    bf16x8 a0 = ldb8(a0p + k0), a1 = ldb8(a1p + k0);
    bf16x8 b0 = ldb8(b0p + k0), b1 = ldb8(b1p + k0);
    acc[0][0] = mfma32(a0, b0, acc[0][0]);
    acc[0][1] = mfma32(a0, b1, acc[0][1]);
    acc[1][0] = mfma32(a1, b0, acc[1][0]);
    acc[1][1] = mfma32(a1, b1, acc[1][1]);
  }

  float* Cout = (blockIdx.y == 0) ? mu : logvar;
  int coll0 = wc * 64;                      // local col in [0,128)
#pragma unroll
  for (int ti = 0; ti < 2; ++ti)
#pragma unroll
    for (int tj = 0; tj < 2; ++tj)
#pragma unroll
      for (int r = 0; r < 16; ++r) {
        int row = row0 + ti * 32 + (r & 3) + 8 * (r >> 2) + 4 * (lane >> 5);
        int col = coll0 + tj * 32 + lm;
        Cout[(size_t)row * HD2 + col] = acc[ti][tj][r];
      }
}

// ---------------- SpMM (CSR gather, wave-per-node, bf16 rows 512B) ----------------
// out[i,:] = bf16( maybe_relu( sum_e val[e]*dense[dst[e],:] ) ), D = 256 bf16

template <int RELU>
__global__ __launch_bounds__(256) void k_spmm_b(
    const int* __restrict__ off, const int* __restrict__ dstp,
    const float* __restrict__ valp, const unsigned short* __restrict__ dense,
    unsigned short* __restrict__ outb) {
  int node = blockIdx.x * 4 + (threadIdx.x >> 6);
  int lane = threadIdx.x & 63;
  int l31 = lane & 31;
  int e0 = off[node];
  int e1 = (node == NN - 1) ? EE : off[node + 1];
  const ushort4* dp = (const ushort4*)dense;   // row = 64 ushort4 (512B)
  float a0 = 0.f, a1 = 0.f, a2 = 0.f, a3 = 0.f;
  int eb = e0;
  for (; eb + 32 <= e1; eb += 32) {
    int dd = dstp[eb + l31];
    float vv = valp[eb + l31];
#pragma unroll
    for (int j = 0; j < 32; ++j) {
      int dj = __shfl(dd, j);
      float vj = __shfl(vv, j);
      ushort4 r = dp[(size_t)dj * 64 + lane];
      a0 = fmaf(vj, b2f(r.x), a0);
      a1 = fmaf(vj, b2f(r.y), a1);
      a2 = fmaf(vj, b2f(r.z), a2);
      a3 = fmaf(vj, b2f(r.w), a3);
    }
  }
  int rem = e1 - eb;
  if (rem > 0) {
    int dd = 0; float vv = 0.f;
    if (l31 < rem) { dd = dstp[eb + l31]; vv = valp[eb + l31]; }
    for (int j = 0; j < rem; ++j) {
      int dj = __shfl(dd, j);
      float vj = __shfl(vv, j);
      ushort4 r = dp[(size_t)dj * 64 + lane];
      a0 = fmaf(vj, b2f(r.x), a0);
      a1 = fmaf(vj, b2f(r.y), a1);
      a2 = fmaf(vj, b2f(r.z), a2);
      a3 = fmaf(vj, b2f(r.w), a3);
    }
  }
  if (RELU) {
    a0 = fmaxf(a0, 0.f); a1 = fmaxf(a1, 0.f);
    a2 = fmaxf(a2, 0.f); a3 = fmaxf(a3, 0.f);
  }
  ushort4 ob;
  ob.x = f2b(a0); ob.y = f2b(a1); ob.z = f2b(a2); ob.w = f2b(a3);
  ((ushort4*)outb)[(size_t)node * 64 + lane] = ob;
}

// ---------------- Z fragment swizzle ----------------
// zf chunk t (8 bf16, 16B): t = (R*8 + C)*64 + lane;
// element j of chunk = Z[R*32 + (lane&31)][C*16 + (lane>>5)*8 + j]
__global__ void k_zf(const float* __restrict__ mu, unsigned short* __restrict__ zf) {
  int t = blockIdx.x * 256 + threadIdx.x;      // t < NN*HD2/8 = 196608
  int lane = t & 63;
  int C = (t >> 6) & 7;
  int R = t >> 9;
  int srow = R * 32 + (lane & 31);
  int scol = C * 16 + (lane >> 5) * 8;
  const float* s = mu + (size_t)srow * HD2 + scol;
  float4 v0 = ((const float4*)s)[0];
  float4 v1 = ((const float4*)s)[1];
  ushort4 o0, o1;
  o0.x = f2b(v0.x); o0.y = f2b(v0.y); o0.z = f2b(v0.z); o0.w = f2b(v0.w);
  o1.x = f2b(v1.x); o1.y = f2b(v1.y); o1.z = f2b(v1.z); o1.w = f2b(v1.w);
  ((ushort4*)zf)[2 * t]     = o0;
  ((ushort4*)zf)[2 * t + 1] = o1;
}

// ---------------- Decoder: out = sigmoid(Z * Z^T) ----------------

// fragment-major zf variant, 128x256 tile, 512 threads (8 waves = 2x4)
__global__ __launch_bounds__(512) void k_decoder_z(const unsigned short* __restrict__ zf,
                                                   float* __restrict__ out) {
  int wave = threadIdx.x >> 6, lane = threadIdx.x & 63;
  int wr = wave >> 2, wc = wave & 3;
  int row0 = blockIdx.x * 128 + wr * 64;
  int col0 = blockIdx.y * 256 + wc * 64;
  int lm = lane & 31;
  int aR = row0 >> 5;
  int bR = col0 >> 5;
  const unsigned short* ap = zf + ((size_t)aR * 8 * 64 + lane) * 8;
  const unsigned short* bp = zf + ((size_t)bR * 8 * 64 + lane) * 8;

  f32x16 acc[2][2] = {};
#pragma unroll
  for (int C = 0; C < 8; ++C) {
    bf16x8 a0 = ldb8(ap + C * 512);
    bf16x8 a1 = ldb8(ap + 4096 + C * 512);
    bf16x8 b0 = ldb8(bp + C * 512);
    bf16x8 b1 = ldb8(bp + 4096 + C * 512);
    acc[0][0] = mfma32(a0, b0, acc[0][0]);
    acc[0][1] = mfma32(a0, b1, acc[0][1]);
    acc[1][0] = mfma32(a1, b0, acc[1][0]);
    acc[1][1] = mfma32(a1, b1, acc[1][1]);
  }

#pragma unroll
  for (int ti = 0; ti < 2; ++ti)
#pragma unroll
    for (int tj = 0; tj < 2; ++tj)
#pragma unroll
      for (int r = 0; r < 16; ++r) {
        int row = row0 + ti * 32 + (r & 3) + 8 * (r >> 2) + 4 * (lane >> 5);
        int col = col0 + tj * 32 + lm;
        float s = sigmoid_fast(acc[ti][tj][r]);
        __builtin_nontemporal_store(s, &out[(size_t)row * NN + col]);
      }
}

// fp32-Z fallback when ws is too small for zf
__global__ __launch_bounds__(256) void k_decoder(const float* __restrict__ Zf,
                                                 float* __restrict__ out) {
  int wave = threadIdx.x >> 6, lane = threadIdx.x & 63;
  int wr = wave >> 1, wc = wave & 1;
  int row0 = blockIdx.x * 128 + wr * 64;
  int col0 = blockIdx.y * 128 + wc * 64;
  int lm = lane & 31, lk = (lane >> 5) * 8;

  f32x16 acc[2][2] = {};
  const float* a0p = Zf + (size_t)(row0 + lm) * HD2 + lk;
  const float* a1p = a0p + (size_t)32 * HD2;
  const float* b0p = Zf + (size_t)(col0 + lm) * HD2 + lk;
  const float* b1p = b0p + (size_t)32 * HD2;

#pragma unroll
  for (int k0 = 0; k0 < HD2; k0 += 16) {
    bf16x8 a0 = ldf8(a0p + k0), a1 = ldf8(a1p + k0);
    bf16x8 b0 = ldf8(b0p + k0), b1 = ldf8(b1p + k0);
    acc[0][0] = mfma32(a0, b0, acc[0][0]);
    acc[0][1] = mfma32(a0, b1, acc[0][1]);
    acc[1][0] = mfma32(a1, b0, acc[1][0]);
    acc[1][1] = mfma32(a1, b1, acc[1][1]);
  }

#pragma unroll
  for (int ti = 0; ti < 2; ++ti)
#pragma unroll
    for (int tj = 0; tj < 2; ++tj)
#pragma unroll
      for (int r = 0; r < 16; ++r) {
        int row = row0 + ti * 32 + (r & 3) + 8 * (r >> 2) + 4 * (lane >> 5);
        int col = col0 + tj * 32 + lm;
        float s = sigmoid_fast(acc[ti][tj][r]);
        __builtin_nontemporal_store(s, &out[(size_t)row * NN + col]);
      }
}

// ---------------- launch ----------------

extern "C" void kernel_launch(void* const* d_in, const int* in_sizes, int n_in,
                              void* d_out, int out_size, void* d_ws, size_t ws_size,
                              hipStream_t stream) {
  const float* x  = (const float*)d_in[0];
  const int*   src = (const int*)d_in[1];
  const int*   dst = (const int*)d_in[2];
  const float* ev  = (const float*)d_in[3];
  const float* W1  = (const float*)d_in[4];
  const float* W2  = (const float*)d_in[5];
  const float* W3  = (const float*)d_in[6];
  float* out = (float*)d_out;
  float* mu     = out + (size_t)NN * NN;
  float* logvar = mu + (size_t)NN * HD2;

  // Scratch lives inside out[0 : NN*NN] (604 MB; we need ~40 MB). Every
  // scratch byte is dead before the decoder overwrites the region.
  char* p = (char*)d_out;
  auto alloc = [&](size_t bytes) {
    char* r = p;
    p += (bytes + 255) & ~(size_t)255;
    return r;
  };
  unsigned short* xb    = (unsigned short*)alloc((size_t)NN * FF * 2);
  unsigned short* W1t   = (unsigned short*)alloc((size_t)HD1 * FF * 2);
  unsigned short* W23t  = (unsigned short*)alloc((size_t)2 * HD2 * HD1 * 2);
  unsigned short* sup1b = (unsigned short*)alloc((size_t)NN * HD1 * 2);
  unsigned short* h1b   = (unsigned short*)alloc((size_t)NN * HD1 * 2);
  unsigned short* aggh  = (unsigned short*)alloc((size_t)NN * HD1 * 2);
  int* deg  = (int*)alloc(NN * 4);
  int* off  = (int*)alloc(NN * 4);
  int* cur  = (int*)alloc(NN * 4);
  int*   dstp = (int*)alloc((size_t)EE * 4);
  float* valp = (float*)alloc((size_t)EE * 4);
  int*   bsum = (int*)alloc((NN / 256) * 4);

  // fragment-major bf16 Z in d_ws (3.15 MB); must NOT live inside
  // out[0:NN*NN] (decoder overwrites that region while blocks still read Z).
  const size_t zf_bytes = (size_t)NN * HD2 * 2;
  bool use_zf = (d_ws != nullptr) && (ws_size >= zf_bytes + 256);
  unsigned short* zf = (unsigned short*)d_ws;

  // CSR build on src (permuting dst/val into CSR order) + fused prep
  hipMemsetAsync(deg, 0, NN * 4, stream);
  {
    int prep_total = PREP_NX + PREP_NW1 + 2 * PREP_NW23;
    int nb = HIST_NB + (prep_total + 255) / 256;
    k_hist_prep<<<nb, 256, 0, stream>>>(src, deg, x, xb, W1, W1t, W2, W3, W23t);
  }
  k_scan1<<<NN / 256, 256, 0, stream>>>(deg, off, bsum);
  k_scan2<<<1, 64, 0, stream>>>(bsum);
  k_scan3<<<NN / 256, 256, 0, stream>>>(bsum, off, cur);
  k_fill<<<EE / 256, 256, 0, stream>>>(src, dst, ev, cur, dstp, valp);

  // encoder layer 1: sup1b = bf16(x @ W1) ; h1b = bf16(relu(spmm(sup1b)))
  gemm_btb<FF><<<dim3(NN / 128, HD1 / 128), 256, 0, stream>>>(xb, W1t, sup1b, HD1);
  k_spmm_b<1><<<NN / 4, 256, 0, stream>>>(off, dstp, valp, sup1b, h1b);

  // encoder layer 2 (SpMM-first; spmm commutes with @W):
  // aggh = bf16(spmm(h1b)) ; [mu|logvar] = aggh @ [W2|W3]
  k_spmm_b<0><<<NN / 4, 256, 0, stream>>>(off, dstp, valp, h1b, aggh);
  gemm_mlv<<<dim3(NN / 128, 2), 256, 0, stream>>>(aggh, W23t, mu, logvar);

  // decoder: out[0 : NN*NN] = sigmoid(z z^T), z = mu (eval mode)
  if (use_zf) {
    k_zf<<<(NN * HD2 / 8) / 256, 256, 0, stream>>>(mu, zf);
    k_decoder_z<<<dim3(NN / 128, NN / 256), 512, 0, stream>>>(zf, out);
  } else {
    k_decoder<<<dim3(NN / 128, NN / 128), 256, 0, stream>>>(mu, out);
  }
}